// Round 2
// baseline (656.536 us; speedup 1.0000x reference)
//
#include <hip/hip_runtime.h>

namespace {
constexpr int E_N  = 131072;
constexpr int FEA  = 256;
constexpr int RAD  = 64;
constexpr int HID  = 128;
constexpr int WN   = 256;
constexpr int EPB  = 64;    // edges per block (= 64 lanes)
constexpr int NT   = 256;   // 4 waves
constexpr int LSTR = 65;    // len tile stride (bank = (lane+k)%32, 2-way free)
constexpr int ASTR = 129;   // silu tile stride (bank = (lane+k)%32, 2-way free)
}

__global__ __launch_bounds__(NT, 4)
void fused_mlp_dtp(
    const float* __restrict__ fea_a, const float* __restrict__ vec_a,
    const float* __restrict__ len_a, const float* __restrict__ W1_a,
    const float* __restrict__ b1_a,  const float* __restrict__ g_a,
    const float* __restrict__ be_a,  const float* __restrict__ W2_a,
    const float* __restrict__ fea_b, const float* __restrict__ vec_b,
    const float* __restrict__ len_b, const float* __restrict__ W1_b,
    const float* __restrict__ b1_b,  const float* __restrict__ g_b,
    const float* __restrict__ be_b,  const float* __restrict__ W2_b,
    float* __restrict__ out)
{
    // sBuf aliases: phase 1-2 it is the len tile [64][65]; after the partials
    // barrier it becomes the silu tile [64][129].
    __shared__ float sBuf[EPB * ASTR];    // 33 KB
    __shared__ float sS [4 * EPB];        // 1 KB  LN partial sums
    __shared__ float sS2[4 * EPB];        // 1 KB  LN partial sq-sums

    const int pipe = blockIdx.y;
    const float* __restrict__ fea = pipe ? fea_b : fea_a;
    const float* __restrict__ vec = pipe ? vec_b : vec_a;
    const float* __restrict__ len = pipe ? len_b : len_a;
    const float* __restrict__ W1  = pipe ? W1_b  : W1_a;
    const float* __restrict__ b1  = pipe ? b1_b  : b1_a;
    const float* __restrict__ g   = pipe ? g_b   : g_a;
    const float* __restrict__ be  = pipe ? be_b  : be_a;
    const float* __restrict__ W2  = pipe ? W2_b  : W2_a;
    float* __restrict__ outp = out + (size_t)pipe * (size_t)E_N * FEA;

    const int t    = threadIdx.x;
    const int lane = t & 63;                                    // = edge in tile
    const int wv_  = __builtin_amdgcn_readfirstlane(t >> 6);    // wave id -> SGPR
    const long e0  = (long)blockIdx.x * EPB;

    // ---------- Phase 1: stage len tile [64][65] ----------
    {
        const float4* __restrict__ src = (const float4*)(len + e0 * RAD);
        #pragma unroll
        for (int i = 0; i < (EPB * RAD / 4) / NT; ++i) {
            const int f = t + i * NT;            // 0..1023
            const float4 v = src[f];
            const int e = f >> 4, kq = (f & 15) * 4;
            float* d = &sBuf[e * LSTR + kq];
            d[0] = v.x; d[1] = v.y; d[2] = v.z; d[3] = v.w;
        }
    }
    __syncthreads();

    // ---------- Phase 2: h = len @ W1 + b1 ; wave's cols [32w,32w+32), lane=edge
    float h[32];
    {
        #pragma unroll
        for (int j = 0; j < 32; ++j) h[j] = 0.f;
        const int cb = wv_ * 32;
        for (int k = 0; k < RAD; ++k) {
            const float a = sBuf[lane * LSTR + k];               // 2-way, free
            const float4* __restrict__ W1r = (const float4*)(W1 + (size_t)k * HID + cb);
            #pragma unroll
            for (int j = 0; j < 8; ++j) {                        // uniform -> s_load
                const float4 wv = W1r[j];
                h[4*j+0] += a * wv.x;
                h[4*j+1] += a * wv.y;
                h[4*j+2] += a * wv.z;
                h[4*j+3] += a * wv.w;
            }
        }
        const float4* __restrict__ b1r = (const float4*)(b1 + cb);
        #pragma unroll
        for (int j = 0; j < 8; ++j) {
            const float4 bv = b1r[j];
            h[4*j+0] += bv.x; h[4*j+1] += bv.y; h[4*j+2] += bv.z; h[4*j+3] += bv.w;
        }
    }

    // ---------- LN partials (register -> tiny LDS, cross-wave) ----------
    {
        float s = 0.f, s2 = 0.f;
        #pragma unroll
        for (int j = 0; j < 32; ++j) { s += h[j]; s2 += h[j] * h[j]; }
        sS [wv_ * EPB + lane] = s;
        sS2[wv_ * EPB + lane] = s2;
    }
    __syncthreads();   // after this, len region of sBuf is dead everywhere

    // ---------- LN finalize + SiLU, write silu tile [64][129] ----------
    {
        float S = 0.f, S2 = 0.f;
        #pragma unroll
        for (int j = 0; j < 4; ++j) { S += sS[j * EPB + lane]; S2 += sS2[j * EPB + lane]; }
        const float mu  = S * (1.0f / HID);
        const float var = S2 * (1.0f / HID) - mu * mu;
        const float inv = rsqrtf(var + 1e-5f);
        const int cb = wv_ * 32;
        const float4* __restrict__ gr  = (const float4*)(g  + cb);
        const float4* __restrict__ ber = (const float4*)(be + cb);
        #pragma unroll
        for (int j = 0; j < 8; ++j) {
            const float4 gv = gr[j];
            const float4 bv = ber[j];
            const float hn0 = (h[4*j+0] - mu) * inv * gv.x + bv.x;
            const float hn1 = (h[4*j+1] - mu) * inv * gv.y + bv.y;
            const float hn2 = (h[4*j+2] - mu) * inv * gv.z + bv.z;
            const float hn3 = (h[4*j+3] - mu) * inv * gv.w + bv.w;
            sBuf[lane * ASTR + cb + 4*j + 0] = hn0 / (1.0f + __expf(-hn0));
            sBuf[lane * ASTR + cb + 4*j + 1] = hn1 / (1.0f + __expf(-hn1));
            sBuf[lane * ASTR + cb + 4*j + 2] = hn2 / (1.0f + __expf(-hn2));
            sBuf[lane * ASTR + cb + 4*j + 3] = hn3 / (1.0f + __expf(-hn3));
        }
    }
    __syncthreads();

    // ---------- Phase 4: w = silu @ W2 ; wave's u-stripe [16w,16w+16) ----------
    // lane=edge holds all four w-components (u, 64+u, 128+u, 192+u) for its u's.
    float a0[16], a1[16], a2[16], a3[16];
    {
        #pragma unroll
        for (int j = 0; j < 16; ++j) { a0[j]=0.f; a1[j]=0.f; a2[j]=0.f; a3[j]=0.f; }
        const int ub = wv_ * 16;
        for (int k = 0; k < HID; ++k) {
            const float a = sBuf[lane * ASTR + k];               // 2-way, free
            const float* __restrict__ W2r = W2 + (size_t)k * WN;
            const float4* __restrict__ p0 = (const float4*)(W2r + ub);
            const float4* __restrict__ p1 = (const float4*)(W2r + 64  + ub);
            const float4* __restrict__ p2 = (const float4*)(W2r + 128 + ub);
            const float4* __restrict__ p3 = (const float4*)(W2r + 192 + ub);
            #pragma unroll
            for (int j = 0; j < 4; ++j) {                        // uniform -> s_load
                const float4 q0 = p0[j], q1 = p1[j], q2 = p2[j], q3 = p3[j];
                a0[4*j+0] += a * q0.x; a0[4*j+1] += a * q0.y; a0[4*j+2] += a * q0.z; a0[4*j+3] += a * q0.w;
                a1[4*j+0] += a * q1.x; a1[4*j+1] += a * q1.y; a1[4*j+2] += a * q1.z; a1[4*j+3] += a * q1.w;
                a2[4*j+0] += a * q2.x; a2[4*j+1] += a * q2.y; a2[4*j+2] += a * q2.z; a2[4*j+3] += a * q2.w;
                a3[4*j+0] += a * q3.x; a3[4*j+1] += a * q3.y; a3[4*j+2] += a * q3.z; a3[4*j+3] += a * q3.w;
            }
        }
    }

    // ---------- Epilogue: DTP, lane-local; full-line reads/writes per lane ----
    {
        const int ub = wv_ * 16;
        const long eg = e0 + lane;
        const float4 y = *(const float4*)(vec + eg * 4);
        const float* __restrict__ fr   = fea  + eg * (size_t)FEA;
        float* __restrict__       orow = outp + eg * (size_t)FEA;
        const float c2 = 0.70710678118654752f;                   // 1/sqrt(2)
        const float c3 = 0.40824829046386302f;                   // 1/sqrt(6)
        #pragma unroll
        for (int j4 = 0; j4 < 4; ++j4) {
            const float4 x0 = *(const float4*)(fr + ub + 4*j4);
            const float4 xA = *(const float4*)(fr + 64 + 3*ub + 12*j4 + 0);
            const float4 xB = *(const float4*)(fr + 64 + 3*ub + 12*j4 + 4);
            const float4 xC = *(const float4*)(fr + 64 + 3*ub + 12*j4 + 8);
            const float x0s[4] = {x0.x, x0.y, x0.z, x0.w};
            const float x1a[4] = {xA.x, xA.w, xB.z, xC.y};
            const float x1b[4] = {xA.y, xB.x, xB.w, xC.z};
            const float x1c[4] = {xA.z, xB.y, xC.x, xC.w};
            float o0[4], oa[4], ob[4], oc[4];
            #pragma unroll
            for (int m = 0; m < 4; ++m) {
                const int i = 4*j4 + m;
                const float w1 = a0[i], w2 = a1[i], w3 = a2[i], w4 = a3[i];
                const float dot = x1a[m]*y.y + x1b[m]*y.z + x1c[m]*y.w;
                o0[m] = w1 * x0s[m] * y.x * c2 + w4 * dot * c3;
                oa[m] = (w2 * x0s[m] * y.y + w3 * x1a[m] * y.x) * c2;
                ob[m] = (w2 * x0s[m] * y.z + w3 * x1b[m] * y.x) * c2;
                oc[m] = (w2 * x0s[m] * y.w + w3 * x1c[m] * y.x) * c2;
            }
            *(float4*)(orow + ub + 4*j4) = make_float4(o0[0], o0[1], o0[2], o0[3]);
            *(float4*)(orow + 64 + 3*ub + 12*j4 + 0) = make_float4(oa[0], ob[0], oc[0], oa[1]);
            *(float4*)(orow + 64 + 3*ub + 12*j4 + 4) = make_float4(ob[1], oc[1], oa[2], ob[2]);
            *(float4*)(orow + 64 + 3*ub + 12*j4 + 8) = make_float4(oc[2], oa[3], ob[3], oc[3]);
        }
    }
}

extern "C" void kernel_launch(void* const* d_in, const int* in_sizes, int n_in,
                              void* d_out, int out_size, void* d_ws, size_t ws_size,
                              hipStream_t stream) {
    (void)in_sizes; (void)n_in; (void)d_ws; (void)ws_size; (void)out_size;
    const float* fea_a = (const float*)d_in[0];
    const float* vec_a = (const float*)d_in[1];
    const float* len_a = (const float*)d_in[2];
    const float* W1_a  = (const float*)d_in[3];
    const float* b1_a  = (const float*)d_in[4];
    const float* g_a   = (const float*)d_in[5];
    const float* be_a  = (const float*)d_in[6];
    const float* W2_a  = (const float*)d_in[7];
    const float* fea_b = (const float*)d_in[8];
    const float* vec_b = (const float*)d_in[9];
    const float* len_b = (const float*)d_in[10];
    const float* W1_b  = (const float*)d_in[11];
    const float* b1_b  = (const float*)d_in[12];
    const float* g_b   = (const float*)d_in[13];
    const float* be_b  = (const float*)d_in[14];
    const float* W2_b  = (const float*)d_in[15];
    float* out = (float*)d_out;

    dim3 grid(E_N / EPB, 2);
    dim3 block(NT);
    hipLaunchKernelGGL(fused_mlp_dtp, grid, block, 0, stream,
                       fea_a, vec_a, len_a, W1_a, b1_a, g_a, be_a, W2_a,
                       fea_b, vec_b, len_b, W1_b, b1_b, g_b, be_b, W2_b,
                       out);
}

// Round 4
// 384.266 us; speedup vs baseline: 1.7085x; 1.7085x over previous
//
#include <hip/hip_runtime.h>

namespace {
constexpr int E_N  = 131072;
constexpr int FEA  = 256;
constexpr int RAD  = 64;
constexpr int HID  = 128;
constexpr int WN   = 256;
constexpr int EPB  = 64;    // edges per block
constexpr int NT   = 256;   // 4 waves
constexpr int ASTR = 132;   // sAct stride: 132%32=4 -> 4-way max, 16B-aligned rows
}

__global__ __launch_bounds__(NT, 3)
void fused_mlp_dtp(
    const float* __restrict__ fea_a, const float* __restrict__ vec_a,
    const float* __restrict__ len_a, const float* __restrict__ W1_a,
    const float* __restrict__ b1_a,  const float* __restrict__ g_a,
    const float* __restrict__ be_a,  const float* __restrict__ W2_a,
    const float* __restrict__ fea_b, const float* __restrict__ vec_b,
    const float* __restrict__ len_b, const float* __restrict__ W1_b,
    const float* __restrict__ b1_b,  const float* __restrict__ g_b,
    const float* __restrict__ be_b,  const float* __restrict__ W2_b,
    float* __restrict__ out)
{
    __shared__ float sLen[EPB * RAD];   // 16 KB; linear [e][k]; reused as out1 stage
    __shared__ float sAct[EPB * ASTR];  // 33 KB

    const int pipe = blockIdx.y;
    const float* __restrict__ fea = pipe ? fea_b : fea_a;
    const float* __restrict__ vec = pipe ? vec_b : vec_a;
    const float* __restrict__ len = pipe ? len_b : len_a;
    const float* __restrict__ W1  = pipe ? W1_b  : W1_a;
    const float* __restrict__ b1  = pipe ? b1_b  : b1_a;
    const float* __restrict__ g   = pipe ? g_b   : g_a;
    const float* __restrict__ be  = pipe ? be_b  : be_a;
    const float* __restrict__ W2  = pipe ? W2_b  : W2_a;
    float* __restrict__ outp = out + (size_t)pipe * (size_t)E_N * FEA;

    const int t    = threadIdx.x;
    const int lane = t & 63;
    const int wv_  = t >> 6;
    const long e0  = (long)blockIdx.x * EPB;

    // ---------- Phase 1: stage len tile [64][64] (linear copy, round-1) -----
    {
        const float4* __restrict__ src = (const float4*)(len + e0 * RAD);
        float4* dst = (float4*)sLen;
        #pragma unroll
        for (int i = 0; i < (EPB * RAD / 4) / NT; ++i)
            dst[t + i * NT] = src[t + i * NT];
    }
    __syncthreads();

    // ---------- Phase 2: h = len @ W1 + b1 -> sAct (k vectorized by 4) ------
    {
        const int c0 = (t & 31) * 4;        // col block 0..124
        const int eb = (t >> 5) * 8;        // edge block 0..56
        float acc[8][4];
        #pragma unroll
        for (int i = 0; i < 8; ++i)
            #pragma unroll
            for (int j = 0; j < 4; ++j) acc[i][j] = 0.f;

        for (int kg = 0; kg < RAD / 4; ++kg) {
            const float4 w0 = *(const float4*)(W1 + (size_t)(kg*4 + 0) * HID + c0);
            const float4 w1 = *(const float4*)(W1 + (size_t)(kg*4 + 1) * HID + c0);
            const float4 w2 = *(const float4*)(W1 + (size_t)(kg*4 + 2) * HID + c0);
            const float4 w3 = *(const float4*)(W1 + (size_t)(kg*4 + 3) * HID + c0);
            #pragma unroll
            for (int i = 0; i < 8; ++i) {
                const float4 lv = *(const float4*)(&sLen[(eb + i) * RAD + kg * 4]);
                acc[i][0] += lv.x*w0.x + lv.y*w1.x + lv.z*w2.x + lv.w*w3.x;
                acc[i][1] += lv.x*w0.y + lv.y*w1.y + lv.z*w2.y + lv.w*w3.y;
                acc[i][2] += lv.x*w0.z + lv.y*w1.z + lv.z*w2.z + lv.w*w3.z;
                acc[i][3] += lv.x*w0.w + lv.y*w1.w + lv.z*w2.w + lv.w*w3.w;
            }
        }
        const float4 bv = *(const float4*)(b1 + c0);
        #pragma unroll
        for (int i = 0; i < 8; ++i) {
            const float4 o = make_float4(acc[i][0] + bv.x, acc[i][1] + bv.y,
                                         acc[i][2] + bv.z, acc[i][3] + bv.w);
            *(float4*)(&sAct[(eb + i) * ASTR + c0]) = o;
        }
    }
    __syncthreads();   // sLen dead from here on

    // ---------- Phase 3: LayerNorm + SiLU (round-1 mapping, b128 access) ----
    {
        const int e = t >> 2;               // 0..63
        const int q = t & 3;                // 4 threads/edge, 32 cols each
        float* __restrict__ row = &sAct[e * ASTR + q * 32];
        float hv[32];
        float s = 0.f, s2 = 0.f;
        #pragma unroll
        for (int j = 0; j < 8; ++j) {
            const float4 v = *(const float4*)(row + 4 * j);
            hv[4*j+0] = v.x; hv[4*j+1] = v.y; hv[4*j+2] = v.z; hv[4*j+3] = v.w;
            s  += v.x + v.y + v.z + v.w;
            s2 += v.x*v.x + v.y*v.y + v.z*v.z + v.w*v.w;
        }
        s  += __shfl_xor(s, 1);  s  += __shfl_xor(s, 2);
        s2 += __shfl_xor(s2, 1); s2 += __shfl_xor(s2, 2);
        const float mu  = s * (1.0f / HID);
        float var = s2 * (1.0f / HID) - mu * mu;
        var = fmaxf(var, 0.0f);                     // guard rsqrt(neg)
        const float inv = rsqrtf(var + 1e-5f);
        const float4* __restrict__ gr  = (const float4*)(g  + q * 32);
        const float4* __restrict__ ber = (const float4*)(be + q * 32);
        #pragma unroll
        for (int j = 0; j < 8; ++j) {
            const float4 gv = gr[j];
            const float4 bv = ber[j];
            const float h0 = (hv[4*j+0] - mu) * inv * gv.x + bv.x;
            const float h1 = (hv[4*j+1] - mu) * inv * gv.y + bv.y;
            const float h2 = (hv[4*j+2] - mu) * inv * gv.z + bv.z;
            const float h3 = (hv[4*j+3] - mu) * inv * gv.w + bv.w;
            float4 o;
            o.x = h0 / (1.0f + __expf(-h0));
            o.y = h1 / (1.0f + __expf(-h1));
            o.z = h2 / (1.0f + __expf(-h2));
            o.w = h3 / (1.0f + __expf(-h3));
            *(float4*)(row + 4 * j) = o;
        }
    }
    __syncthreads();

    // ---------- Phase 4: w = silu @ W2 (lane=u, b128 broadcast, kg by 4) ----
    float a0[16], a1[16], a2[16], a3[16];
    {
        const int u   = lane;
        const int eb4 = wv_ * 16;
        #pragma unroll
        for (int i = 0; i < 16; ++i) { a0[i]=0.f; a1[i]=0.f; a2[i]=0.f; a3[i]=0.f; }

        for (int kg = 0; kg < HID / 4; ++kg) {
            float w[4][4];
            #pragma unroll
            for (int kk = 0; kk < 4; ++kk) {
                const float* __restrict__ Wr = W2 + (size_t)(kg * 4 + kk) * WN;
                w[kk][0] = Wr[u];       w[kk][1] = Wr[64  + u];   // coalesced b32
                w[kk][2] = Wr[128 + u]; w[kk][3] = Wr[192 + u];
            }
            #pragma unroll
            for (int i = 0; i < 16; ++i) {
                const float4 av = *(const float4*)(&sAct[(eb4 + i) * ASTR + kg * 4]);
                a0[i] += av.x*w[0][0] + av.y*w[1][0] + av.z*w[2][0] + av.w*w[3][0];
                a1[i] += av.x*w[0][1] + av.y*w[1][1] + av.z*w[2][1] + av.w*w[3][1];
                a2[i] += av.x*w[0][2] + av.y*w[1][2] + av.z*w[2][2] + av.w*w[3][2];
                a3[i] += av.x*w[0][3] + av.y*w[1][3] + av.z*w[2][3] + av.w*w[3][3];
            }
        }
    }
    // No barrier needed here: epilogue stage uses sLen region (dead since
    // phase 2->3 barrier); phase 4 reads only sAct.

    // ---------- Epilogue: DTP; out0 direct, out1 via barriered LDS stage ----
    {
        const int u = lane;
        const long ebase = e0 + wv_ * 16;
        float* sStage = sLen + wv_ * 768;            // 3 KB per wave, disjoint
        const float c2 = 0.70710678118654752f;       // 1/sqrt(2)
        const float c3 = 0.40824829046386302f;       // 1/sqrt(6)

        for (int ch = 0; ch < 4; ++ch) {
            #pragma unroll
            for (int m = 0; m < 4; ++m) {
                const int i = ch * 4 + m;
                const long e = ebase + i;
                const float4 y = *(const float4*)(vec + e * 4);
                const float* __restrict__ fr = fea + e * (size_t)FEA;
                const float x0  = fr[u];
                const float x1a = fr[64 + 3*u + 0];
                const float x1b = fr[64 + 3*u + 1];
                const float x1c = fr[64 + 3*u + 2];
                const float w1 = a0[i], w2 = a1[i], w3 = a2[i], w4 = a3[i];
                const float dot = x1a*y.y + x1b*y.z + x1c*y.w;
                outp[e * (size_t)FEA + u] = w1*x0*y.x*c2 + w4*dot*c3;  // 256B/instr
                sStage[m*192 + 3*u + 0] = (w2*x0*y.y + w3*x1a*y.x) * c2;
                sStage[m*192 + 3*u + 1] = (w2*x0*y.z + w3*x1b*y.x) * c2;
                sStage[m*192 + 3*u + 2] = (w2*x0*y.w + w3*x1c*y.x) * c2;
            }
            __syncthreads();   // stage complete (convergent: all waves, all ch)
            #pragma unroll
            for (int r = 0; r < 3; ++r) {
                const int flat = r * 256 + u * 4;    // 0..764, 16B aligned
                const int eloc = flat / 192;
                const int pos  = flat % 192;
                const float4 v = *(const float4*)(&sStage[flat]);
                *(float4*)(&outp[(ebase + ch*4 + eloc) * (size_t)FEA + 64 + pos]) = v;
            }
            __syncthreads();   // drain complete before next ch overwrites
        }
    }
}

extern "C" void kernel_launch(void* const* d_in, const int* in_sizes, int n_in,
                              void* d_out, int out_size, void* d_ws, size_t ws_size,
                              hipStream_t stream) {
    (void)in_sizes; (void)n_in; (void)d_ws; (void)ws_size; (void)out_size;
    const float* fea_a = (const float*)d_in[0];
    const float* vec_a = (const float*)d_in[1];
    const float* len_a = (const float*)d_in[2];
    const float* W1_a  = (const float*)d_in[3];
    const float* b1_a  = (const float*)d_in[4];
    const float* g_a   = (const float*)d_in[5];
    const float* be_a  = (const float*)d_in[6];
    const float* W2_a  = (const float*)d_in[7];
    const float* fea_b = (const float*)d_in[8];
    const float* vec_b = (const float*)d_in[9];
    const float* len_b = (const float*)d_in[10];
    const float* W1_b  = (const float*)d_in[11];
    const float* b1_b  = (const float*)d_in[12];
    const float* g_b   = (const float*)d_in[13];
    const float* be_b  = (const float*)d_in[14];
    const float* W2_b  = (const float*)d_in[15];
    float* out = (float*)d_out;

    dim3 grid(E_N / EPB, 2);
    dim3 block(NT);
    hipLaunchKernelGGL(fused_mlp_dtp, grid, block, 0, stream,
                       fea_a, vec_a, len_a, W1_a, b1_a, g_a, be_a, W2_a,
                       fea_b, vec_b, len_b, W1_b, b1_b, g_b, be_b, W2_b,
                       out);
}

// Round 8
// 343.474 us; speedup vs baseline: 1.9115x; 1.1188x over previous
//
#include <hip/hip_runtime.h>

namespace {
constexpr int E_N  = 131072;
constexpr int FEA  = 256;
constexpr int RAD  = 64;
constexpr int HID  = 128;
constexpr int WN   = 256;
constexpr int EPB  = 64;    // edges per block
constexpr int NT   = 256;   // 4 waves
constexpr int ASTR = 132;   // sAct stride: 132%32=4 -> 4-way max, 16B-aligned rows
}

typedef float float2v __attribute__((ext_vector_type(2)));

// One VOP3P packed FMA: {d.x,d.y} = {a.x*b.x+c.x, a.y*b.y+c.y}
__device__ __forceinline__ float2v pkfma(float2v a, float2v b, float2v c) {
    float2v d;
    asm("v_pk_fma_f32 %0, %1, %2, %3" : "=v"(d) : "v"(a), "v"(b), "v"(c));
    return d;
}
__device__ __forceinline__ float2v mk2(float a, float b) {
    float2v r; r.x = a; r.y = b; return r;
}

__global__ __launch_bounds__(NT, 3)
void fused_mlp_dtp(
    const float* __restrict__ fea_a, const float* __restrict__ vec_a,
    const float* __restrict__ len_a, const float* __restrict__ W1_a,
    const float* __restrict__ b1_a,  const float* __restrict__ g_a,
    const float* __restrict__ be_a,  const float* __restrict__ W2_a,
    const float* __restrict__ fea_b, const float* __restrict__ vec_b,
    const float* __restrict__ len_b, const float* __restrict__ W1_b,
    const float* __restrict__ b1_b,  const float* __restrict__ g_b,
    const float* __restrict__ be_b,  const float* __restrict__ W2_b,
    float* __restrict__ out)
{
    __shared__ float sLen[EPB * RAD];   // 16 KB; reused as out1 stage in epilogue
    __shared__ float sAct[EPB * ASTR];  // 33 KB

    const int pipe = blockIdx.y;
    const float* __restrict__ fea = pipe ? fea_b : fea_a;
    const float* __restrict__ vec = pipe ? vec_b : vec_a;
    const float* __restrict__ len = pipe ? len_b : len_a;
    const float* __restrict__ W1  = pipe ? W1_b  : W1_a;
    const float* __restrict__ b1  = pipe ? b1_b  : b1_a;
    const float* __restrict__ g   = pipe ? g_b   : g_a;
    const float* __restrict__ be  = pipe ? be_b  : be_a;
    const float* __restrict__ W2  = pipe ? W2_b  : W2_a;
    float* __restrict__ outp = out + (size_t)pipe * (size_t)E_N * FEA;

    const int t    = threadIdx.x;
    const int lane = t & 63;
    const int wv_  = t >> 6;
    const long e0  = (long)blockIdx.x * EPB;

    // ---------- Phase 1: stage len tile [64][64] ----------
    {
        const float4* __restrict__ src = (const float4*)(len + e0 * RAD);
        float4* dst = (float4*)sLen;
        #pragma unroll
        for (int i = 0; i < (EPB * RAD / 4) / NT; ++i)
            dst[t + i * NT] = src[t + i * NT];
    }
    __syncthreads();

    // ---------- Phase 2: h = len @ W1 + b1 -> sAct (pk-FMA over k-pairs) ----
    {
        const int c0 = (t & 31) * 4;        // col block 0..124
        const int eb = (t >> 5) * 8;        // edge block 0..56
        float2v acc2[8][4];                 // [edge][col], pair = (k even, k odd)
        #pragma unroll
        for (int i = 0; i < 8; ++i)
            #pragma unroll
            for (int j = 0; j < 4; ++j) { acc2[i][j].x = 0.f; acc2[i][j].y = 0.f; }

        for (int kg = 0; kg < RAD / 4; ++kg) {
            const float4 w0 = *(const float4*)(W1 + (size_t)(kg*4 + 0) * HID + c0);
            const float4 w1 = *(const float4*)(W1 + (size_t)(kg*4 + 1) * HID + c0);
            const float4 w2 = *(const float4*)(W1 + (size_t)(kg*4 + 2) * HID + c0);
            const float4 w3 = *(const float4*)(W1 + (size_t)(kg*4 + 3) * HID + c0);
            const float2v wp0[4] = { mk2(w0.x,w1.x), mk2(w0.y,w1.y),
                                     mk2(w0.z,w1.z), mk2(w0.w,w1.w) };
            const float2v wp1[4] = { mk2(w2.x,w3.x), mk2(w2.y,w3.y),
                                     mk2(w2.z,w3.z), mk2(w2.w,w3.w) };
            #pragma unroll
            for (int i = 0; i < 8; ++i) {
                const float4 lv = *(const float4*)(&sLen[(eb + i) * RAD + kg * 4]);
                const float2v a01 = mk2(lv.x, lv.y);
                const float2v a23 = mk2(lv.z, lv.w);
                #pragma unroll
                for (int c = 0; c < 4; ++c) {
                    acc2[i][c] = pkfma(a01, wp0[c], acc2[i][c]);
                    acc2[i][c] = pkfma(a23, wp1[c], acc2[i][c]);
                }
            }
        }
        const float4 bv = *(const float4*)(b1 + c0);
        #pragma unroll
        for (int i = 0; i < 8; ++i) {
            const float4 o = make_float4(acc2[i][0].x + acc2[i][0].y + bv.x,
                                         acc2[i][1].x + acc2[i][1].y + bv.y,
                                         acc2[i][2].x + acc2[i][2].y + bv.z,
                                         acc2[i][3].x + acc2[i][3].y + bv.w);
            *(float4*)(&sAct[(eb + i) * ASTR + c0]) = o;
        }
    }
    __syncthreads();   // sLen dead from here on

    // ---------- Phase 3: LayerNorm + SiLU (round-4 verbatim) ----------
    {
        const int e = t >> 2;               // 0..63
        const int q = t & 3;                // 4 threads/edge, 32 cols each
        float* __restrict__ row = &sAct[e * ASTR + q * 32];
        float hv[32];
        float s = 0.f, s2 = 0.f;
        #pragma unroll
        for (int j = 0; j < 8; ++j) {
            const float4 v = *(const float4*)(row + 4 * j);
            hv[4*j+0] = v.x; hv[4*j+1] = v.y; hv[4*j+2] = v.z; hv[4*j+3] = v.w;
            s  += v.x + v.y + v.z + v.w;
            s2 += v.x*v.x + v.y*v.y + v.z*v.z + v.w*v.w;
        }
        s  += __shfl_xor(s, 1);  s  += __shfl_xor(s, 2);
        s2 += __shfl_xor(s2, 1); s2 += __shfl_xor(s2, 2);
        const float mu  = s * (1.0f / HID);
        float var = s2 * (1.0f / HID) - mu * mu;
        var = fmaxf(var, 0.0f);                     // guard rsqrt(neg)
        const float inv = rsqrtf(var + 1e-5f);
        const float4* __restrict__ gr  = (const float4*)(g  + q * 32);
        const float4* __restrict__ ber = (const float4*)(be + q * 32);
        #pragma unroll
        for (int j = 0; j < 8; ++j) {
            const float4 gv = gr[j];
            const float4 bv = ber[j];
            const float h0 = (hv[4*j+0] - mu) * inv * gv.x + bv.x;
            const float h1 = (hv[4*j+1] - mu) * inv * gv.y + bv.y;
            const float h2 = (hv[4*j+2] - mu) * inv * gv.z + bv.z;
            const float h3 = (hv[4*j+3] - mu) * inv * gv.w + bv.w;
            float4 o;
            o.x = h0 / (1.0f + __expf(-h0));
            o.y = h1 / (1.0f + __expf(-h1));
            o.z = h2 / (1.0f + __expf(-h2));
            o.w = h3 / (1.0f + __expf(-h3));
            *(float4*)(row + 4 * j) = o;
        }
    }
    __syncthreads();

    // ---------- Phase 4: w = silu @ W2 (pk-FMA over k-pairs) ----------
    float a0[16], a1[16], a2[16], a3[16];
    {
        const int u   = lane;
        const int eb4 = wv_ * 16;
        float2v acc2[16][4];                // [edge][comp], pair over k parity
        #pragma unroll
        for (int i = 0; i < 16; ++i)
            #pragma unroll
            for (int c = 0; c < 4; ++c) { acc2[i][c].x = 0.f; acc2[i][c].y = 0.f; }

        for (int kg = 0; kg < HID / 4; ++kg) {
            float w[4][4];                  // [kk][comp]
            #pragma unroll
            for (int kk = 0; kk < 4; ++kk) {
                const float* __restrict__ Wr = W2 + (size_t)(kg * 4 + kk) * WN;
                w[kk][0] = Wr[u];       w[kk][1] = Wr[64  + u];   // coalesced b32
                w[kk][2] = Wr[128 + u]; w[kk][3] = Wr[192 + u];
            }
            const float2v wp0[4] = { mk2(w[0][0], w[1][0]), mk2(w[0][1], w[1][1]),
                                     mk2(w[0][2], w[1][2]), mk2(w[0][3], w[1][3]) };
            const float2v wp1[4] = { mk2(w[2][0], w[3][0]), mk2(w[2][1], w[3][1]),
                                     mk2(w[2][2], w[3][2]), mk2(w[2][3], w[3][3]) };
            #pragma unroll
            for (int i = 0; i < 16; ++i) {
                const float4 av = *(const float4*)(&sAct[(eb4 + i) * ASTR + kg * 4]);
                const float2v a01 = mk2(av.x, av.y);
                const float2v a23 = mk2(av.z, av.w);
                #pragma unroll
                for (int c = 0; c < 4; ++c) {
                    acc2[i][c] = pkfma(a01, wp0[c], acc2[i][c]);
                    acc2[i][c] = pkfma(a23, wp1[c], acc2[i][c]);
                }
            }
        }
        #pragma unroll
        for (int i = 0; i < 16; ++i) {
            a0[i] = acc2[i][0].x + acc2[i][0].y;
            a1[i] = acc2[i][1].x + acc2[i][1].y;
            a2[i] = acc2[i][2].x + acc2[i][2].y;
            a3[i] = acc2[i][3].x + acc2[i][3].y;
        }
    }
    // No barrier needed here: epilogue stage uses sLen region (dead since
    // phase 2->3 barrier); phase 4 read only this wave's own sAct rows.

    // ---------- Epilogue: DTP; out0 direct, out1 via barriered LDS stage ----
    {
        const int u = lane;
        const long ebase = e0 + wv_ * 16;
        float* sStage = sLen + wv_ * 768;            // 3 KB per wave, disjoint
        const float c2 = 0.70710678118654752f;       // 1/sqrt(2)
        const float c3 = 0.40824829046386302f;       // 1/sqrt(6)

        for (int ch = 0; ch < 4; ++ch) {
            #pragma unroll
            for (int m = 0; m < 4; ++m) {
                const int i = ch * 4 + m;
                const long e = ebase + i;
                const float4 y = *(const float4*)(vec + e * 4);
                const float* __restrict__ fr = fea + e * (size_t)FEA;
                const float x0  = fr[u];
                const float x1a = fr[64 + 3*u + 0];
                const float x1b = fr[64 + 3*u + 1];
                const float x1c = fr[64 + 3*u + 2];
                const float w1 = a0[i], w2 = a1[i], w3 = a2[i], w4 = a3[i];
                const float dot = x1a*y.y + x1b*y.z + x1c*y.w;
                outp[e * (size_t)FEA + u] = w1*x0*y.x*c2 + w4*dot*c3;  // 256B/instr
                sStage[m*192 + 3*u + 0] = (w2*x0*y.y + w3*x1a*y.x) * c2;
                sStage[m*192 + 3*u + 1] = (w2*x0*y.z + w3*x1b*y.x) * c2;
                sStage[m*192 + 3*u + 2] = (w2*x0*y.w + w3*x1c*y.x) * c2;
            }
            __syncthreads();   // stage complete (convergent: all waves, all ch)
            #pragma unroll
            for (int r = 0; r < 3; ++r) {
                const int flat = r * 256 + u * 4;    // 0..764, 16B aligned
                const int eloc = flat / 192;
                const int pos  = flat % 192;
                const float4 v = *(const float4*)(&sStage[flat]);
                *(float4*)(&outp[(ebase + ch*4 + eloc) * (size_t)FEA + 64 + pos]) = v;
            }
            __syncthreads();   // drain complete before next ch overwrites
        }
    }
}

extern "C" void kernel_launch(void* const* d_in, const int* in_sizes, int n_in,
                              void* d_out, int out_size, void* d_ws, size_t ws_size,
                              hipStream_t stream) {
    (void)in_sizes; (void)n_in; (void)d_ws; (void)ws_size; (void)out_size;
    const float* fea_a = (const float*)d_in[0];
    const float* vec_a = (const float*)d_in[1];
    const float* len_a = (const float*)d_in[2];
    const float* W1_a  = (const float*)d_in[3];
    const float* b1_a  = (const float*)d_in[4];
    const float* g_a   = (const float*)d_in[5];
    const float* be_a  = (const float*)d_in[6];
    const float* W2_a  = (const float*)d_in[7];
    const float* fea_b = (const float*)d_in[8];
    const float* vec_b = (const float*)d_in[9];
    const float* len_b = (const float*)d_in[10];
    const float* W1_b  = (const float*)d_in[11];
    const float* b1_b  = (const float*)d_in[12];
    const float* g_b   = (const float*)d_in[13];
    const float* be_b  = (const float*)d_in[14];
    const float* W2_b  = (const float*)d_in[15];
    float* out = (float*)d_out;

    dim3 grid(E_N / EPB, 2);
    dim3 block(NT);
    hipLaunchKernelGGL(fused_mlp_dtp, grid, block, 0, stream,
                       fea_a, vec_a, len_a, W1_a, b1_a, g_a, be_a, W2_a,
                       fea_b, vec_b, len_b, W1_b, b1_b, g_b, be_b, W2_b,
                       out);
}